// Round 1
// baseline (17127.463 us; speedup 1.0000x reference)
//
#include <hip/hip_runtime.h>

#define BB 64
#define TT 512
#define EE 512
#define HH 1024
#define NCLS 5
#define NWG 128

typedef __attribute__((ext_vector_type(8))) short bfrag;
typedef __attribute__((ext_vector_type(4))) float facc;

// ---- workspace layout (bytes) ----
#define XE_OFF   0                                   // [T][B][E] bf16
#define HBUF_OFF (XE_OFF + (size_t)TT * BB * EE * 2) // 2 x [B][H] bf16
#define FEAT_OFF (HBUF_OFF + (size_t)2 * BB * HH * 2)// [B][H] f32
#define SYNC_OFF (FEAT_OFF + (size_t)BB * HH * 4)    // 1024 B of sync ints

static __device__ __forceinline__ unsigned short f2bf(float f) {
  unsigned int u = __float_as_uint(f);
  u += 0x7fff + ((u >> 16) & 1);   // RNE
  return (unsigned short)(u >> 16);
}

// ---------------- kernel 1: embedding gather -> bf16 xe[t][b][e] ----------------
__global__ __launch_bounds__(256) void k_gather(const int* __restrict__ x,
                                                const float* __restrict__ emb,
                                                unsigned short* __restrict__ xe,
                                                int* __restrict__ sync) {
  if (blockIdx.x == 0 && threadIdx.x < 256) sync[threadIdx.x] = 0;  // zero barrier state every launch
  int wave = (blockIdx.x * 256 + threadIdx.x) >> 6;  // 0..32767
  int lane = threadIdx.x & 63;
  int t = wave >> 6;
  int b = wave & 63;
  int tok = x[b * TT + t];
  const float* src = emb + (size_t)tok * EE + lane * 8;
  float4 f0 = ((const float4*)src)[0];
  float4 f1 = ((const float4*)src)[1];
  uint4 pk;
  pk.x = (unsigned)f2bf(f0.x) | ((unsigned)f2bf(f0.y) << 16);
  pk.y = (unsigned)f2bf(f0.z) | ((unsigned)f2bf(f0.w) << 16);
  pk.z = (unsigned)f2bf(f1.x) | ((unsigned)f2bf(f1.y) << 16);
  pk.w = (unsigned)f2bf(f1.z) | ((unsigned)f2bf(f1.w) << 16);
  *(uint4*)(xe + ((size_t)t * BB + b) * EE + lane * 8) = pk;
}

// ---------------- kernel 2: persistent LSTM recurrence ----------------
// 128 WGs x 256 threads. WG w owns h indices [w*8, w*8+8): 32 rows of [W_ih|W_hh] in LDS.
// LDS row r: gate g=r>>3 (i,f,g,o), jh=r&7 -> global row g*1024 + w*8 + jh.
__global__ __launch_bounds__(256) void k_lstm(const float* __restrict__ W_ih,
                                              const float* __restrict__ W_hh,
                                              const float* __restrict__ b_ih,
                                              const float* __restrict__ b_hh,
                                              const unsigned short* __restrict__ xe,
                                              unsigned short* __restrict__ hbuf,
                                              float* __restrict__ feat,
                                              int* __restrict__ sync) {
  __shared__ unsigned short Wlds[32][1544];  // 1536 + 8 pad: stride=772 words = 4 banks mod 32 (2-way, free)
  __shared__ float bias_lds[32];

  const int w = blockIdx.x;
  const int tid = threadIdx.x;

  // ---- load W slice (fp32 -> bf16) ----
  for (int idx = tid; idx < 32 * 512; idx += 256) {
    int r = idx >> 9, k = idx & 511;
    int R = (r >> 3) * 1024 + w * 8 + (r & 7);
    Wlds[r][k] = f2bf(W_ih[(size_t)R * EE + k]);
  }
  for (int idx = tid; idx < 32 * 1024; idx += 256) {
    int r = idx >> 10, k = idx & 1023;
    int R = (r >> 3) * 1024 + w * 8 + (r & 7);
    Wlds[r][512 + k] = f2bf(W_hh[(size_t)R * HH + k]);
  }
  if (tid < 32) {
    int R = (tid >> 3) * 1024 + w * 8 + (tid & 7);
    bias_lds[tid] = b_ih[R] + b_hh[R];
  }
  __syncthreads();

  const int lane = tid & 63;
  const int wm = tid >> 6;        // wave id: batch tile (16 rows)
  const int c15 = lane & 15;      // A m-row / C col within tile
  const int kq = lane >> 4;       // k-group
  const int k0 = kq * 8;
  const int bA = wm * 16 + c15;   // batch row this lane loads for A-frags

  const unsigned short* wl0 = &Wlds[c15][k0];       // n-tile 0: rows 0..15 (i,f)
  const unsigned short* wl1 = &Wlds[16 + c15][k0];  // n-tile 1: rows 16..31 (g,o)
  const float bias0 = bias_lds[c15];
  const float bias1 = bias_lds[16 + c15];

  float cst[4]  = {0.f, 0.f, 0.f, 0.f};
  float hmax[4] = {-1e30f, -1e30f, -1e30f, -1e30f};

  unsigned short* h0 = hbuf;
  unsigned short* h1 = hbuf + BB * HH;
  int* cnt8 = sync;         // 8 counters, 64B apart
  int* root = sync + 128;
  int* gen  = sync + 144;

  const size_t xe_lane = (size_t)bA * EE + k0;
  const size_t h_lane  = (size_t)bA * HH + k0;

  for (int t = 0; t < TT; ++t) {
    facc a0 = {0.f,0.f,0.f,0.f}, a1 = a0, a2 = a0, a3 = a0;
    const unsigned short* xet = xe + (size_t)t * (BB * EE) + xe_lane;

    // ---- xe-part (h-independent): issue before waiting on the barrier ----
#pragma unroll 4
    for (int kk = 0; kk < 16; kk += 2) {
      bfrag A  = *(const bfrag*)(xet + kk * 32);
      bfrag B0 = *(const bfrag*)(wl0 + kk * 32);
      bfrag B1 = *(const bfrag*)(wl1 + kk * 32);
      a0 = __builtin_amdgcn_mfma_f32_16x16x32_bf16(A, B0, a0, 0, 0, 0);
      a2 = __builtin_amdgcn_mfma_f32_16x16x32_bf16(A, B1, a2, 0, 0, 0);
      bfrag A2  = *(const bfrag*)(xet + kk * 32 + 32);
      bfrag B0b = *(const bfrag*)(wl0 + kk * 32 + 32);
      bfrag B1b = *(const bfrag*)(wl1 + kk * 32 + 32);
      a1 = __builtin_amdgcn_mfma_f32_16x16x32_bf16(A2, B0b, a1, 0, 0, 0);
      a3 = __builtin_amdgcn_mfma_f32_16x16x32_bf16(A2, B1b, a3, 0, 0, 0);
    }

    if (t > 0) {
      if (tid == 0) {
        while (__hip_atomic_load(gen, __ATOMIC_ACQUIRE, __HIP_MEMORY_SCOPE_AGENT) < t)
          __builtin_amdgcn_s_sleep(1);
      }
      __syncthreads();
      __threadfence();  // acquire: invalidate stale cached h
      const unsigned short* hp = ((t & 1) ? h1 : h0) + h_lane;
#pragma unroll 4
      for (int kk = 0; kk < 32; kk += 2) {
        bfrag A  = *(const bfrag*)(hp + kk * 32);
        bfrag B0 = *(const bfrag*)(wl0 + 512 + kk * 32);
        bfrag B1 = *(const bfrag*)(wl1 + 512 + kk * 32);
        a0 = __builtin_amdgcn_mfma_f32_16x16x32_bf16(A, B0, a0, 0, 0, 0);
        a2 = __builtin_amdgcn_mfma_f32_16x16x32_bf16(A, B1, a2, 0, 0, 0);
        bfrag A2  = *(const bfrag*)(hp + kk * 32 + 32);
        bfrag B0b = *(const bfrag*)(wl0 + 512 + kk * 32 + 32);
        bfrag B1b = *(const bfrag*)(wl1 + 512 + kk * 32 + 32);
        a1 = __builtin_amdgcn_mfma_f32_16x16x32_bf16(A2, B0b, a1, 0, 0, 0);
        a3 = __builtin_amdgcn_mfma_f32_16x16x32_bf16(A2, B1b, a3, 0, 0, 0);
      }
    }

    // ---- gates -> c,h.  C-frag: col=lane&15, row=(lane>>4)*4+j ----
    facc X = a0 + a1;  // cols 0..15: i(jh 0-7), f(jh 0-7)
    facc Y = a2 + a3;  // cols 0..15: g(jh 0-7), o(jh 0-7)
    float hv[4];
#pragma unroll
    for (int j = 0; j < 4; ++j) {
      float xv = X[j] + bias0;
      float yv = Y[j] + bias1;
      float xs = __shfl_xor(xv, 8, 64);
      float ys = __shfl_xor(yv, 8, 64);
      bool lo = (c15 < 8);
      float vi = lo ? xv : xs;
      float vf = lo ? xs : xv;
      float vg = lo ? yv : ys;
      float vo = lo ? ys : yv;
      float sf = 1.f / (1.f + __expf(-vf));
      float si = 1.f / (1.f + __expf(-vi));
      float eg = __expf(-2.f * fabsf(vg));
      float tg = copysignf((1.f - eg) / (1.f + eg), vg);
      float cc = sf * cst[j] + si * tg;
      cst[j] = cc;
      float so = 1.f / (1.f + __expf(-vo));
      float ec = __expf(-2.f * fabsf(cc));
      float tc = copysignf((1.f - ec) / (1.f + ec), cc);
      float hh = so * tc;
      hmax[j] = fmaxf(hmax[j], hh);
      hv[j] = hh;
    }

    unsigned short* hn = ((t & 1) ? h0 : h1);  // h(t+1)
    if (c15 < 8) {
      int jh = w * 8 + c15;
#pragma unroll
      for (int j = 0; j < 4; ++j)
        hn[(size_t)(wm * 16 + kq * 4 + j) * HH + jh] = f2bf(hv[j]);
    }

    if (t < TT - 1) {
      __threadfence();   // release h writes to agent scope
      __syncthreads();
      if (tid == 0) {
        int old = __hip_atomic_fetch_add(&cnt8[(w & 7) * 16], 1,
                                         __ATOMIC_ACQ_REL, __HIP_MEMORY_SCOPE_AGENT);
        if (old == 16 * (t + 1) - 1) {
          int o2 = __hip_atomic_fetch_add(root, 1,
                                          __ATOMIC_ACQ_REL, __HIP_MEMORY_SCOPE_AGENT);
          if (o2 == 8 * (t + 1) - 1)
            __hip_atomic_store(gen, t + 1, __ATOMIC_RELEASE, __HIP_MEMORY_SCOPE_AGENT);
        }
      }
    }
  }

  // ---- write temporal-max features ----
  if (c15 < 8) {
    int jh = w * 8 + c15;
#pragma unroll
    for (int j = 0; j < 4; ++j)
      feat[(size_t)(wm * 16 + kq * 4 + j) * HH + jh] = hmax[j];
  }
}

// ---------------- kernel 3: tiny FC ----------------
__global__ __launch_bounds__(64) void k_fc(const float* __restrict__ feat,
                                           const float* __restrict__ W_fc,
                                           const float* __restrict__ b_fc,
                                           float* __restrict__ out) {
  int b = blockIdx.x, cls = blockIdx.y;
  int lane = threadIdx.x;
  const float* f  = feat + (size_t)b * HH;
  const float* wr = W_fc + (size_t)cls * HH;
  float s = 0.f;
  for (int k = lane; k < HH; k += 64) s = fmaf(f[k], wr[k], s);
#pragma unroll
  for (int off = 32; off > 0; off >>= 1) s += __shfl_down(s, off, 64);
  if (lane == 0) out[b * NCLS + cls] = s + b_fc[cls];
}

extern "C" void kernel_launch(void* const* d_in, const int* in_sizes, int n_in,
                              void* d_out, int out_size, void* d_ws, size_t ws_size,
                              hipStream_t stream) {
  const int*   x    = (const int*)d_in[0];
  const float* emb  = (const float*)d_in[1];
  const float* W_ih = (const float*)d_in[2];
  const float* W_hh = (const float*)d_in[3];
  const float* b_ih = (const float*)d_in[4];
  const float* b_hh = (const float*)d_in[5];
  const float* W_fc = (const float*)d_in[6];
  const float* b_fc = (const float*)d_in[7];
  float* out = (float*)d_out;

  char* ws = (char*)d_ws;
  unsigned short* xe   = (unsigned short*)(ws + XE_OFF);
  unsigned short* hbuf = (unsigned short*)(ws + HBUF_OFF);
  float*          feat = (float*)(ws + FEAT_OFF);
  int*            sync = (int*)(ws + SYNC_OFF);

  k_gather<<<dim3(8192), dim3(256), 0, stream>>>(x, emb, xe, sync);
  k_lstm<<<dim3(NWG), dim3(256), 0, stream>>>(W_ih, W_hh, b_ih, b_hh, xe, hbuf, feat, sync);
  k_fc<<<dim3(BB, NCLS), dim3(64), 0, stream>>>(feat, W_fc, b_fc, out);
}

// Round 2
// 4893.295 us; speedup vs baseline: 3.5002x; 3.5002x over previous
//
#include <hip/hip_runtime.h>

#define BB 64
#define TT 512
#define EE 512
#define HH 1024
#define NCLS 5
#define NWG 128

typedef __attribute__((ext_vector_type(8))) short bfrag;
typedef __attribute__((ext_vector_type(4))) float facc;

// ---- workspace layout (bytes) ----
#define XE_OFF   0                                   // [T][B][E] bf16
#define HBUF_OFF (XE_OFF + (size_t)TT * BB * EE * 2) // 2 x [B][H] bf16
#define FEAT_OFF (HBUF_OFF + (size_t)2 * BB * HH * 2)// [B][H] f32
#define SYNC_OFF (FEAT_OFF + (size_t)BB * HH * 4)    // 1024 B of sync ints

static __device__ __forceinline__ unsigned short f2bf(float f) {
  unsigned int u = __float_as_uint(f);
  u += 0x7fff + ((u >> 16) & 1);   // RNE
  return (unsigned short)(u >> 16);
}

// ---- coherent (cross-XCD, MALL-level) access helpers: no cache invalidates ----
static __device__ __forceinline__ void st_u32_sys(unsigned int* p, unsigned int v) {
  asm volatile("global_store_dword %0, %1, off sc0 sc1" :: "v"(p), "v"(v) : "memory");
}
static __device__ __forceinline__ unsigned int ld_u32_sys(const unsigned int* p) {
  unsigned int r;
  asm volatile("global_load_dword %0, %1, off sc0 sc1\n\t"
               "s_waitcnt vmcnt(0)" : "=v"(r) : "v"(p) : "memory");
  return r;
}

// ---------------- kernel 1: embedding gather -> bf16 xe[t][b][e] ----------------
__global__ __launch_bounds__(256) void k_gather(const int* __restrict__ x,
                                                const float* __restrict__ emb,
                                                unsigned short* __restrict__ xe,
                                                int* __restrict__ sync) {
  if (blockIdx.x == 0 && threadIdx.x < 256) sync[threadIdx.x] = 0;  // zero barrier state every launch
  int wave = (blockIdx.x * 256 + threadIdx.x) >> 6;  // 0..32767
  int lane = threadIdx.x & 63;
  int t = wave >> 6;
  int b = wave & 63;
  int tok = x[b * TT + t];
  const float* src = emb + (size_t)tok * EE + lane * 8;
  float4 f0 = ((const float4*)src)[0];
  float4 f1 = ((const float4*)src)[1];
  uint4 pk;
  pk.x = (unsigned)f2bf(f0.x) | ((unsigned)f2bf(f0.y) << 16);
  pk.y = (unsigned)f2bf(f0.z) | ((unsigned)f2bf(f0.w) << 16);
  pk.z = (unsigned)f2bf(f1.x) | ((unsigned)f2bf(f1.y) << 16);
  pk.w = (unsigned)f2bf(f1.z) | ((unsigned)f2bf(f1.w) << 16);
  *(uint4*)(xe + ((size_t)t * BB + b) * EE + lane * 8) = pk;
}

// ---------------- kernel 2: persistent LSTM recurrence ----------------
// 128 WGs x 256 threads. WG w owns h indices [w*8, w*8+8): 32 rows of [W_ih|W_hh] in LDS.
__global__ __launch_bounds__(256, 1) void k_lstm(const float* __restrict__ W_ih,
                                                 const float* __restrict__ W_hh,
                                                 const float* __restrict__ b_ih,
                                                 const float* __restrict__ b_hh,
                                                 const unsigned short* __restrict__ xe,
                                                 unsigned short* __restrict__ hbuf,
                                                 float* __restrict__ feat,
                                                 int* __restrict__ sync) {
  __shared__ unsigned short Wlds[32][1544];  // stride 772 words = 4 banks mod 32
  __shared__ float bias_lds[32];

  const int w = blockIdx.x;
  const int tid = threadIdx.x;

  // ---- load W slice (fp32 -> bf16) ----
  for (int idx = tid; idx < 32 * 512; idx += 256) {
    int r = idx >> 9, k = idx & 511;
    int R = (r >> 3) * 1024 + w * 8 + (r & 7);
    Wlds[r][k] = f2bf(W_ih[(size_t)R * EE + k]);
  }
  for (int idx = tid; idx < 32 * 1024; idx += 256) {
    int r = idx >> 10, k = idx & 1023;
    int R = (r >> 3) * 1024 + w * 8 + (r & 7);
    Wlds[r][512 + k] = f2bf(W_hh[(size_t)R * HH + k]);
  }
  if (tid < 32) {
    int R = (tid >> 3) * 1024 + w * 8 + (tid & 7);
    bias_lds[tid] = b_ih[R] + b_hh[R];
  }
  __syncthreads();

  const int lane = tid & 63;
  const int wm = tid >> 6;        // wave id: batch tile (16 rows)
  const int c15 = lane & 15;      // A m-row / C col within tile
  const int kq = lane >> 4;       // k-group
  const int k0 = kq * 8;
  const int bA = wm * 16 + c15;   // batch row this lane loads for A-frags

  const unsigned short* wl0 = &Wlds[c15][k0];       // n-tile 0: rows 0..15 (i,f)
  const unsigned short* wl1 = &Wlds[16 + c15][k0];  // n-tile 1: rows 16..31 (g,o)
  const float bias0 = bias_lds[c15];
  const float bias1 = bias_lds[16 + c15];

  float cst[4]  = {0.f, 0.f, 0.f, 0.f};
  float hmax[4] = {-1e30f, -1e30f, -1e30f, -1e30f};

  unsigned short* h0 = hbuf;
  unsigned short* h1 = hbuf + BB * HH;
  unsigned int* flags = (unsigned int*)sync;        // flags[w] at sync[w], w<128
  unsigned int* gen   = (unsigned int*)(sync + 200);

  const size_t xe_lane = (size_t)bA * EE + k0;
  const size_t h_lane  = (size_t)bA * HH + k0;

  for (int t = 0; t < TT; ++t) {
    facc a0 = {0.f,0.f,0.f,0.f}, a1 = a0, a2 = a0, a3 = a0;
    const unsigned short* xet = xe + (size_t)t * (BB * EE) + xe_lane;

    // ---- xe-part (h-independent): overlaps the wait ----
#pragma unroll 4
    for (int kk = 0; kk < 16; kk += 2) {
      bfrag A  = *(const bfrag*)(xet + kk * 32);
      bfrag B0 = *(const bfrag*)(wl0 + kk * 32);
      bfrag B1 = *(const bfrag*)(wl1 + kk * 32);
      a0 = __builtin_amdgcn_mfma_f32_16x16x32_bf16(A, B0, a0, 0, 0, 0);
      a2 = __builtin_amdgcn_mfma_f32_16x16x32_bf16(A, B1, a2, 0, 0, 0);
      bfrag A2  = *(const bfrag*)(xet + kk * 32 + 32);
      bfrag B0b = *(const bfrag*)(wl0 + kk * 32 + 32);
      bfrag B1b = *(const bfrag*)(wl1 + kk * 32 + 32);
      a1 = __builtin_amdgcn_mfma_f32_16x16x32_bf16(A2, B0b, a1, 0, 0, 0);
      a3 = __builtin_amdgcn_mfma_f32_16x16x32_bf16(A2, B1b, a3, 0, 0, 0);
    }

    if (t > 0) {
      // ---- barrier wait: WG0 aggregates flags, publishes gen; all poll gen ----
      if (w == 0 && tid < NWG) {
        const unsigned int* fp = flags + tid;
        while (ld_u32_sys(fp) < (unsigned)t) {}
      }
      __syncthreads();
      if (w == 0 && tid == 0) st_u32_sys(gen, (unsigned)t);
      if (tid == 0) {
        while (ld_u32_sys(gen) < (unsigned)t) {}
      }
      __syncthreads();

      // ---- h A-frags: batch-issue 32 coherent 16B loads, single drain ----
      const unsigned short* hp = ((t & 1) ? h1 : h0) + h_lane;
      bfrag hA[32];
#pragma unroll
      for (int i = 0; i < 32; ++i)
        asm volatile("global_load_dwordx4 %0, %1, off sc0 sc1"
                     : "=v"(hA[i]) : "v"(hp + i * 32));
      __builtin_amdgcn_sched_barrier(0);
      asm volatile("s_waitcnt vmcnt(0)" ::: "memory");
      __builtin_amdgcn_sched_barrier(0);

#pragma unroll
      for (int kk = 0; kk < 32; kk += 2) {
        bfrag B0 = *(const bfrag*)(wl0 + 512 + kk * 32);
        bfrag B1 = *(const bfrag*)(wl1 + 512 + kk * 32);
        a0 = __builtin_amdgcn_mfma_f32_16x16x32_bf16(hA[kk], B0, a0, 0, 0, 0);
        a2 = __builtin_amdgcn_mfma_f32_16x16x32_bf16(hA[kk], B1, a2, 0, 0, 0);
        bfrag B0b = *(const bfrag*)(wl0 + 512 + (kk + 1) * 32);
        bfrag B1b = *(const bfrag*)(wl1 + 512 + (kk + 1) * 32);
        a1 = __builtin_amdgcn_mfma_f32_16x16x32_bf16(hA[kk + 1], B0b, a1, 0, 0, 0);
        a3 = __builtin_amdgcn_mfma_f32_16x16x32_bf16(hA[kk + 1], B1b, a3, 0, 0, 0);
      }
    }

    // ---- gates -> c,h.  C-frag: col=lane&15, row=(lane>>4)*4+j ----
    facc X = a0 + a1;  // cols 0..15: i(jh 0-7), f(jh 0-7)
    facc Y = a2 + a3;  // cols 0..15: g(jh 0-7), o(jh 0-7)
    unsigned int hb[4];
#pragma unroll
    for (int j = 0; j < 4; ++j) {
      float xv = X[j] + bias0;
      float yv = Y[j] + bias1;
      float xs = __shfl_xor(xv, 8, 64);
      float ys = __shfl_xor(yv, 8, 64);
      bool lo = (c15 < 8);
      float vi = lo ? xv : xs;
      float vf = lo ? xs : xv;
      float vg = lo ? yv : ys;
      float vo = lo ? ys : yv;
      float sf = 1.f / (1.f + __expf(-vf));
      float si = 1.f / (1.f + __expf(-vi));
      float eg = __expf(-2.f * fabsf(vg));
      float tg = copysignf((1.f - eg) / (1.f + eg), vg);
      float cc = sf * cst[j] + si * tg;
      cst[j] = cc;
      float so = 1.f / (1.f + __expf(-vo));
      float ec = __expf(-2.f * fabsf(cc));
      float tc = copysignf((1.f - ec) / (1.f + ec), cc);
      float hh = so * tc;
      hmax[j] = fmaxf(hmax[j], hh);
      hb[j] = f2bf(hh);
    }

    if (t < TT - 1) {
      // ---- coherent h(t+1) store: pack pairs (c15, c15^1) into u32 ----
      unsigned int* hn32 = (unsigned int*)(((t & 1) ? h0 : h1));
#pragma unroll
      for (int j = 0; j < 4; ++j) {
        unsigned int part = (unsigned int)__shfl_xor((int)hb[j], 1, 64);
        if ((c15 & 1) == 0 && c15 < 8) {
          unsigned int v = (hb[j] & 0xffffu) | (part << 16);
          unsigned int* p = hn32 + (size_t)(wm * 16 + kq * 4 + j) * (HH / 2)
                                 + w * 4 + (c15 >> 1);
          st_u32_sys(p, v);
        }
      }
      asm volatile("s_waitcnt vmcnt(0)" ::: "memory");  // h at MALL before flag
      __syncthreads();
      if (tid == 0) st_u32_sys(flags + w, (unsigned)(t + 1));
    }
  }

  // ---- write temporal-max features ----
  if (c15 < 8) {
    int jh = w * 8 + c15;
#pragma unroll
    for (int j = 0; j < 4; ++j)
      feat[(size_t)(wm * 16 + kq * 4 + j) * HH + jh] = hmax[j];
  }
}

// ---------------- kernel 3: tiny FC ----------------
__global__ __launch_bounds__(64) void k_fc(const float* __restrict__ feat,
                                           const float* __restrict__ W_fc,
                                           const float* __restrict__ b_fc,
                                           float* __restrict__ out) {
  int b = blockIdx.x, cls = blockIdx.y;
  int lane = threadIdx.x;
  const float* f  = feat + (size_t)b * HH;
  const float* wr = W_fc + (size_t)cls * HH;
  float s = 0.f;
  for (int k = lane; k < HH; k += 64) s = fmaf(f[k], wr[k], s);
#pragma unroll
  for (int off = 32; off > 0; off >>= 1) s += __shfl_down(s, off, 64);
  if (lane == 0) out[b * NCLS + cls] = s + b_fc[cls];
}

extern "C" void kernel_launch(void* const* d_in, const int* in_sizes, int n_in,
                              void* d_out, int out_size, void* d_ws, size_t ws_size,
                              hipStream_t stream) {
  const int*   x    = (const int*)d_in[0];
  const float* emb  = (const float*)d_in[1];
  const float* W_ih = (const float*)d_in[2];
  const float* W_hh = (const float*)d_in[3];
  const float* b_ih = (const float*)d_in[4];
  const float* b_hh = (const float*)d_in[5];
  const float* W_fc = (const float*)d_in[6];
  const float* b_fc = (const float*)d_in[7];
  float* out = (float*)d_out;

  char* ws = (char*)d_ws;
  unsigned short* xe   = (unsigned short*)(ws + XE_OFF);
  unsigned short* hbuf = (unsigned short*)(ws + HBUF_OFF);
  float*          feat = (float*)(ws + FEAT_OFF);
  int*            sync = (int*)(ws + SYNC_OFF);

  k_gather<<<dim3(8192), dim3(256), 0, stream>>>(x, emb, xe, sync);
  k_lstm<<<dim3(NWG), dim3(256), 0, stream>>>(W_ih, W_hh, b_ih, b_hh, xe, hbuf, feat, sync);
  k_fc<<<dim3(BB, NCLS), dim3(64), 0, stream>>>(feat, W_fc, b_fc, out);
}

// Round 3
// 4846.794 us; speedup vs baseline: 3.5338x; 1.0096x over previous
//
#include <hip/hip_runtime.h>

#define BB 64
#define TT 512
#define EE 512
#define HH 1024
#define NCLS 5
#define NWG 128

typedef __attribute__((ext_vector_type(8))) short bfrag;
typedef __attribute__((ext_vector_type(4))) float facc;

// ---- workspace layout (bytes), FEAT/SYNC before HBUF so fallback also fits ----
#define XE_BYTES   ((size_t)TT * BB * EE * 2)        // 32 MB
#define FEAT_BYTES ((size_t)BB * HH * 4)             // 256 KB
#define SYNC_BYTES ((size_t)4096)
#define HBUF_FULL  ((size_t)TT * BB * HH * 2)        // 64 MB (full-T, never-reused addresses)
#define HBUF_SMALL ((size_t)2 * BB * HH * 2)         // 256 KB (double-buffer fallback)

static __device__ __forceinline__ unsigned short f2bf(float f) {
  unsigned int u = __float_as_uint(f);
  u += 0x7fff + ((u >> 16) & 1);   // RNE
  return (unsigned short)(u >> 16);
}

// ---- coherent (cross-XCD, MALL-level) helpers: no wholesale cache invalidates ----
static __device__ __forceinline__ void st_u32_sys(unsigned int* p, unsigned int v) {
  asm volatile("global_store_dword %0, %1, off sc0 sc1" :: "v"(p), "v"(v) : "memory");
}
static __device__ __forceinline__ unsigned int ld_u32_sys(const unsigned int* p) {
  unsigned int r;
  asm volatile("global_load_dword %0, %1, off sc0 sc1\n\t"
               "s_waitcnt vmcnt(0)" : "=v"(r) : "v"(p) : "memory");
  return r;
}
// two coherent dword loads, single drain (one MALL round trip per poll iter)
static __device__ __forceinline__ void ld2_u32_sys(const unsigned int* p0,
                                                   const unsigned int* p1,
                                                   unsigned int& a, unsigned int& b) {
  asm volatile("global_load_dword %0, %2, off sc0 sc1\n\t"
               "global_load_dword %1, %3, off sc0 sc1\n\t"
               "s_waitcnt vmcnt(0)"
               : "=v"(a), "=v"(b) : "v"(p0), "v"(p1) : "memory");
}

// ---------------- kernel 1: embedding gather -> bf16 xe[t][b][e] ----------------
__global__ __launch_bounds__(256) void k_gather(const int* __restrict__ x,
                                                const float* __restrict__ emb,
                                                unsigned short* __restrict__ xe,
                                                int* __restrict__ sync) {
  if (blockIdx.x == 0 && threadIdx.x < 256) sync[threadIdx.x] = 0;  // zero flags every launch
  int wave = (blockIdx.x * 256 + threadIdx.x) >> 6;  // 0..32767
  int lane = threadIdx.x & 63;
  int t = wave >> 6;
  int b = wave & 63;
  int tok = x[b * TT + t];
  const float* src = emb + (size_t)tok * EE + lane * 8;
  float4 f0 = ((const float4*)src)[0];
  float4 f1 = ((const float4*)src)[1];
  uint4 pk;
  pk.x = (unsigned)f2bf(f0.x) | ((unsigned)f2bf(f0.y) << 16);
  pk.y = (unsigned)f2bf(f0.z) | ((unsigned)f2bf(f0.w) << 16);
  pk.z = (unsigned)f2bf(f1.x) | ((unsigned)f2bf(f1.y) << 16);
  pk.w = (unsigned)f2bf(f1.z) | ((unsigned)f2bf(f1.w) << 16);
  *(uint4*)(xe + ((size_t)t * BB + b) * EE + lane * 8) = pk;
}

// ---------------- kernel 2: persistent LSTM recurrence ----------------
// 128 WGs x 256 threads. WG w owns h indices [w*8, w*8+8): 32 rows of [W_ih|W_hh] in LDS.
// FULLT: h exchanged via never-reused per-step buffers -> producers write-through (sc0 sc1),
// consumers use PLAIN cached loads (first toucher per XCD misses to MALL, 15 others hit L2).
template <bool FULLT>
__global__ __launch_bounds__(256, 1) void k_lstm(const float* __restrict__ W_ih,
                                                 const float* __restrict__ W_hh,
                                                 const float* __restrict__ b_ih,
                                                 const float* __restrict__ b_hh,
                                                 const unsigned short* __restrict__ xe,
                                                 unsigned short* __restrict__ hbuf,
                                                 float* __restrict__ feat,
                                                 int* __restrict__ sync) {
  __shared__ unsigned short Wlds[32][1544];  // stride 772 words = 4 banks mod 32
  __shared__ float bias_lds[32];

  const int w = blockIdx.x;
  const int tid = threadIdx.x;

  // ---- load W slice (fp32 -> bf16) ----
  for (int idx = tid; idx < 32 * 512; idx += 256) {
    int r = idx >> 9, k = idx & 511;
    int R = (r >> 3) * 1024 + w * 8 + (r & 7);
    Wlds[r][k] = f2bf(W_ih[(size_t)R * EE + k]);
  }
  for (int idx = tid; idx < 32 * 1024; idx += 256) {
    int r = idx >> 10, k = idx & 1023;
    int R = (r >> 3) * 1024 + w * 8 + (r & 7);
    Wlds[r][512 + k] = f2bf(W_hh[(size_t)R * HH + k]);
  }
  if (tid < 32) {
    int R = (tid >> 3) * 1024 + w * 8 + (tid & 7);
    bias_lds[tid] = b_ih[R] + b_hh[R];
  }
  __syncthreads();

  const int lane = tid & 63;
  const int wm = tid >> 6;        // wave id: batch tile (16 rows)
  const int c15 = lane & 15;      // A m-row / C col within tile
  const int kq = lane >> 4;       // k-group
  const int k0 = kq * 8;
  const int bA = wm * 16 + c15;   // batch row this lane loads for A-frags

  const unsigned short* wl0 = &Wlds[c15][k0];       // n-tile 0: rows 0..15 (i,f)
  const unsigned short* wl1 = &Wlds[16 + c15][k0];  // n-tile 1: rows 16..31 (g,o)
  const float bias0 = bias_lds[c15];
  const float bias1 = bias_lds[16 + c15];

  float cst[4]  = {0.f, 0.f, 0.f, 0.f};
  float hmax[4] = {-1e30f, -1e30f, -1e30f, -1e30f};

  unsigned int* flags = (unsigned int*)sync;   // flags[w], w<128; zeroed by k_gather

  const size_t xe_lane = (size_t)bA * EE + k0;
  const size_t h_lane  = (size_t)bA * HH + k0;
  const unsigned int* fp0 = flags + lane;
  const unsigned int* fp1 = flags + 64 + lane;

  for (int t = 0; t < TT; ++t) {
    facc a0 = {0.f,0.f,0.f,0.f}, a1 = a0, a2 = a0, a3 = a0;
    const unsigned short* xet = xe + (size_t)t * (BB * EE) + xe_lane;

    // ---- xe-part (h-independent): overlaps producers' flag propagation ----
#pragma unroll 4
    for (int kk = 0; kk < 16; kk += 2) {
      bfrag A  = *(const bfrag*)(xet + kk * 32);
      bfrag B0 = *(const bfrag*)(wl0 + kk * 32);
      bfrag B1 = *(const bfrag*)(wl1 + kk * 32);
      a0 = __builtin_amdgcn_mfma_f32_16x16x32_bf16(A, B0, a0, 0, 0, 0);
      a2 = __builtin_amdgcn_mfma_f32_16x16x32_bf16(A, B1, a2, 0, 0, 0);
      bfrag A2  = *(const bfrag*)(xet + kk * 32 + 32);
      bfrag B0b = *(const bfrag*)(wl0 + kk * 32 + 32);
      bfrag B1b = *(const bfrag*)(wl1 + kk * 32 + 32);
      a1 = __builtin_amdgcn_mfma_f32_16x16x32_bf16(A2, B0b, a1, 0, 0, 0);
      a3 = __builtin_amdgcn_mfma_f32_16x16x32_bf16(A2, B1b, a3, 0, 0, 0);
    }

    if (t > 0) {
      // ---- one-hop barrier: every wave polls all 128 producer flags ----
      unsigned int fa, fb;
      do {
        ld2_u32_sys(fp0, fp1, fa, fb);
      } while (__any((int)(min(fa, fb) < (unsigned)t)));
      __builtin_amdgcn_sched_barrier(0);

      if constexpr (FULLT) {
        // plain cached loads from never-before-touched addresses (L2 broadcast)
        const unsigned short* hp = hbuf + (size_t)t * (BB * HH) + h_lane;
#pragma unroll 4
        for (int kk = 0; kk < 32; kk += 2) {
          bfrag A  = *(const bfrag*)(hp + kk * 32);
          bfrag B0 = *(const bfrag*)(wl0 + 512 + kk * 32);
          bfrag B1 = *(const bfrag*)(wl1 + 512 + kk * 32);
          a0 = __builtin_amdgcn_mfma_f32_16x16x32_bf16(A, B0, a0, 0, 0, 0);
          a2 = __builtin_amdgcn_mfma_f32_16x16x32_bf16(A, B1, a2, 0, 0, 0);
          bfrag A2  = *(const bfrag*)(hp + kk * 32 + 32);
          bfrag B0b = *(const bfrag*)(wl0 + 512 + (kk + 1) * 32);
          bfrag B1b = *(const bfrag*)(wl1 + 512 + (kk + 1) * 32);
          a1 = __builtin_amdgcn_mfma_f32_16x16x32_bf16(A2, B0b, a1, 0, 0, 0);
          a3 = __builtin_amdgcn_mfma_f32_16x16x32_bf16(A2, B1b, a3, 0, 0, 0);
        }
      } else {
        // fallback: coherent batched loads, double-buffered h
        const unsigned short* hp = hbuf + ((t & 1) ? (size_t)(BB * HH) : 0) + h_lane;
        bfrag hA[32];
#pragma unroll
        for (int i = 0; i < 32; ++i)
          asm volatile("global_load_dwordx4 %0, %1, off sc0 sc1"
                       : "=v"(hA[i]) : "v"(hp + i * 32));
        __builtin_amdgcn_sched_barrier(0);
        asm volatile("s_waitcnt vmcnt(0)" ::: "memory");
        __builtin_amdgcn_sched_barrier(0);
#pragma unroll
        for (int kk = 0; kk < 32; kk += 2) {
          bfrag B0 = *(const bfrag*)(wl0 + 512 + kk * 32);
          bfrag B1 = *(const bfrag*)(wl1 + 512 + kk * 32);
          a0 = __builtin_amdgcn_mfma_f32_16x16x32_bf16(hA[kk], B0, a0, 0, 0, 0);
          a2 = __builtin_amdgcn_mfma_f32_16x16x32_bf16(hA[kk], B1, a2, 0, 0, 0);
          bfrag B0b = *(const bfrag*)(wl0 + 512 + (kk + 1) * 32);
          bfrag B1b = *(const bfrag*)(wl1 + 512 + (kk + 1) * 32);
          a1 = __builtin_amdgcn_mfma_f32_16x16x32_bf16(hA[kk + 1], B0b, a1, 0, 0, 0);
          a3 = __builtin_amdgcn_mfma_f32_16x16x32_bf16(hA[kk + 1], B1b, a3, 0, 0, 0);
        }
      }
    }

    // ---- gates -> c,h.  C-frag: col=lane&15, row=(lane>>4)*4+j ----
    facc X = a0 + a1;  // cols 0..15: i(jh 0-7), f(jh 0-7)
    facc Y = a2 + a3;  // cols 0..15: g(jh 0-7), o(jh 0-7)
    unsigned int hb[4];
#pragma unroll
    for (int j = 0; j < 4; ++j) {
      float xv = X[j] + bias0;
      float yv = Y[j] + bias1;
      float xs = __shfl_xor(xv, 8, 64);
      float ys = __shfl_xor(yv, 8, 64);
      bool lo = (c15 < 8);
      float vi = lo ? xv : xs;
      float vf = lo ? xs : xv;
      float vg = lo ? yv : ys;
      float vo = lo ? ys : yv;
      float sf = 1.f / (1.f + __expf(-vf));
      float si = 1.f / (1.f + __expf(-vi));
      float eg = __expf(-2.f * fabsf(vg));
      float tg = copysignf((1.f - eg) / (1.f + eg), vg);
      float cc = sf * cst[j] + si * tg;
      cst[j] = cc;
      float so = 1.f / (1.f + __expf(-vo));
      float ec = __expf(-2.f * fabsf(cc));
      float tc = copysignf((1.f - ec) / (1.f + ec), cc);
      float hh = so * tc;
      hmax[j] = fmaxf(hmax[j], hh);
      hb[j] = f2bf(hh);
    }

    if (t < TT - 1) {
      // ---- coherent (write-through) h(t+1) store: pack pairs into u32 ----
      unsigned int* hn32;
      if constexpr (FULLT)
        hn32 = (unsigned int*)(hbuf + (size_t)(t + 1) * (BB * HH));
      else
        hn32 = (unsigned int*)(hbuf + ((t & 1) ? 0 : (size_t)(BB * HH)));
#pragma unroll
      for (int j = 0; j < 4; ++j) {
        unsigned int part = (unsigned int)__shfl_xor((int)hb[j], 1, 64);
        if ((c15 & 1) == 0 && c15 < 8) {
          unsigned int v = (hb[j] & 0xffffu) | (part << 16);
          unsigned int* p = hn32 + (size_t)(wm * 16 + kq * 4 + j) * (HH / 2)
                                 + w * 4 + (c15 >> 1);
          st_u32_sys(p, v);
        }
      }
      asm volatile("s_waitcnt vmcnt(0)" ::: "memory");  // h at MALL before flag
      __syncthreads();
      if (tid == 0) st_u32_sys(flags + w, (unsigned)(t + 1));
    }
  }

  // ---- write temporal-max features ----
  if (c15 < 8) {
    int jh = w * 8 + c15;
#pragma unroll
    for (int j = 0; j < 4; ++j)
      feat[(size_t)(wm * 16 + kq * 4 + j) * HH + jh] = hmax[j];
  }
}

// ---------------- kernel 3: tiny FC ----------------
__global__ __launch_bounds__(64) void k_fc(const float* __restrict__ feat,
                                           const float* __restrict__ W_fc,
                                           const float* __restrict__ b_fc,
                                           float* __restrict__ out) {
  int b = blockIdx.x, cls = blockIdx.y;
  int lane = threadIdx.x;
  const float* f  = feat + (size_t)b * HH;
  const float* wr = W_fc + (size_t)cls * HH;
  float s = 0.f;
  for (int k = lane; k < HH; k += 64) s = fmaf(f[k], wr[k], s);
#pragma unroll
  for (int off = 32; off > 0; off >>= 1) s += __shfl_down(s, off, 64);
  if (lane == 0) out[b * NCLS + cls] = s + b_fc[cls];
}

extern "C" void kernel_launch(void* const* d_in, const int* in_sizes, int n_in,
                              void* d_out, int out_size, void* d_ws, size_t ws_size,
                              hipStream_t stream) {
  const int*   x    = (const int*)d_in[0];
  const float* emb  = (const float*)d_in[1];
  const float* W_ih = (const float*)d_in[2];
  const float* W_hh = (const float*)d_in[3];
  const float* b_ih = (const float*)d_in[4];
  const float* b_hh = (const float*)d_in[5];
  const float* W_fc = (const float*)d_in[6];
  const float* b_fc = (const float*)d_in[7];
  float* out = (float*)d_out;

  char* ws = (char*)d_ws;
  unsigned short* xe   = (unsigned short*)(ws);
  float*          feat = (float*)(ws + XE_BYTES);
  int*            sync = (int*)(ws + XE_BYTES + FEAT_BYTES);
  unsigned short* hbuf = (unsigned short*)(ws + XE_BYTES + FEAT_BYTES + SYNC_BYTES);

  const bool full = (ws_size >= XE_BYTES + FEAT_BYTES + SYNC_BYTES + HBUF_FULL);

  k_gather<<<dim3(8192), dim3(256), 0, stream>>>(x, emb, xe, sync);
  if (full)
    k_lstm<true><<<dim3(NWG), dim3(256), 0, stream>>>(W_ih, W_hh, b_ih, b_hh, xe, hbuf, feat, sync);
  else
    k_lstm<false><<<dim3(NWG), dim3(256), 0, stream>>>(W_ih, W_hh, b_ih, b_hh, xe, hbuf, feat, sync);
  k_fc<<<dim3(BB, NCLS), dim3(64), 0, stream>>>(feat, W_fc, b_fc, out);
}